// Round 1
// baseline (6770.689 us; speedup 1.0000x reference)
//
#include <hip/hip_runtime.h>

#define T_DIM 2048
#define B_DIM 4
#define S_DIM 2048
#define E_DIM 1024
#define H_NUM 16
#define HD    64
#define NH    64      // B*H
#define SP1   2049    // S+1 (bias token appended)
#define SPAD  2112    // 33*64, padded key length
#define NCHUNK 33

// ---------------------------------------------------------------------------
// Tiled f32 GEMM: out[m][n] = sum_k X[m][k] * W[n][k] + bias[n]   (F.linear)
// MODE 0: Q proj  -> scatter to q_h [n][T][64], scaled by 1/8
// MODE 1: K proj  -> scatter to k_h [n][SPAD][64]
// MODE 2: V proj  -> scatter to v_h [n][SPAD][64]
// MODE 3: out proj-> X gathered from attn_h [n][T][64], out row-major [8192][1024]
// ---------------------------------------------------------------------------
template<int MODE>
__global__ __launch_bounds__(256)
void linear_k(const float* __restrict__ X, const float* __restrict__ W,
              const float* __restrict__ bias, float* __restrict__ out)
{
    __shared__ float Xs[64][65];
    __shared__ float Ws[64][65];
    const int bm = blockIdx.x;
    const int bn = blockIdx.y;
    const int tid = threadIdx.x;
    const int ty = tid >> 4;          // 0..15
    const int tx = tid & 15;          // 0..15
    const int lr = tid >> 4;          // load row base
    const int lc = (tid & 15) << 2;   // load col base (floats)

    float acc[4][4] = {};

    for (int k0 = 0; k0 < E_DIM; k0 += 64) {
#pragma unroll
        for (int rr = 0; rr < 4; ++rr) {
            const int row = lr + rr * 16;
            float4 xv;
            if (MODE == 3) {
                const int m = bm * 64 + row;
                const int t = m >> 2, b = m & 3;
                const int head = k0 >> 6;
                xv = *reinterpret_cast<const float4*>(
                    X + (((size_t)(b * 16 + head) * T_DIM + t) * HD + lc));
            } else {
                xv = *reinterpret_cast<const float4*>(
                    X + (size_t)(bm * 64 + row) * E_DIM + k0 + lc);
            }
            Xs[row][lc + 0] = xv.x; Xs[row][lc + 1] = xv.y;
            Xs[row][lc + 2] = xv.z; Xs[row][lc + 3] = xv.w;

            const float4 wv = *reinterpret_cast<const float4*>(
                W + (size_t)(bn * 64 + row) * E_DIM + k0 + lc);
            Ws[row][lc + 0] = wv.x; Ws[row][lc + 1] = wv.y;
            Ws[row][lc + 2] = wv.z; Ws[row][lc + 3] = wv.w;
        }
        __syncthreads();
#pragma unroll 8
        for (int kk = 0; kk < 64; ++kk) {
            const float a0 = Xs[ty * 4 + 0][kk];
            const float a1 = Xs[ty * 4 + 1][kk];
            const float a2 = Xs[ty * 4 + 2][kk];
            const float a3 = Xs[ty * 4 + 3][kk];
            const float b0 = Ws[tx * 4 + 0][kk];
            const float b1 = Ws[tx * 4 + 1][kk];
            const float b2 = Ws[tx * 4 + 2][kk];
            const float b3 = Ws[tx * 4 + 3][kk];
            acc[0][0] = fmaf(a0, b0, acc[0][0]); acc[0][1] = fmaf(a0, b1, acc[0][1]);
            acc[0][2] = fmaf(a0, b2, acc[0][2]); acc[0][3] = fmaf(a0, b3, acc[0][3]);
            acc[1][0] = fmaf(a1, b0, acc[1][0]); acc[1][1] = fmaf(a1, b1, acc[1][1]);
            acc[1][2] = fmaf(a1, b2, acc[1][2]); acc[1][3] = fmaf(a1, b3, acc[1][3]);
            acc[2][0] = fmaf(a2, b0, acc[2][0]); acc[2][1] = fmaf(a2, b1, acc[2][1]);
            acc[2][2] = fmaf(a2, b2, acc[2][2]); acc[2][3] = fmaf(a2, b3, acc[2][3]);
            acc[3][0] = fmaf(a3, b0, acc[3][0]); acc[3][1] = fmaf(a3, b1, acc[3][1]);
            acc[3][2] = fmaf(a3, b2, acc[3][2]); acc[3][3] = fmaf(a3, b3, acc[3][3]);
        }
        __syncthreads();
    }

    // epilogue
    const float bb0 = bias[bn * 64 + tx * 4 + 0];
    const float bb1 = bias[bn * 64 + tx * 4 + 1];
    const float bb2 = bias[bn * 64 + tx * 4 + 2];
    const float bb3 = bias[bn * 64 + tx * 4 + 3];

#pragma unroll
    for (int i = 0; i < 4; ++i) {
        const int m = bm * 64 + ty * 4 + i;
        float4 v;
        v.x = acc[i][0] + bb0; v.y = acc[i][1] + bb1;
        v.z = acc[i][2] + bb2; v.w = acc[i][3] + bb3;
        if (MODE == 3) {
            *reinterpret_cast<float4*>(out + (size_t)m * E_DIM + bn * 64 + tx * 4) = v;
        } else {
            if (MODE == 0) { v.x *= 0.125f; v.y *= 0.125f; v.z *= 0.125f; v.w *= 0.125f; }
            const int sl = m >> 2, b = m & 3;   // row of [L,B,E] -> (l, b)
            const int sd = (MODE == 0) ? T_DIM : SPAD;
            *reinterpret_cast<float4*>(
                out + (((size_t)(b * 16 + bn) * sd + sl) * HD + tx * 4)) = v;
        }
    }
}

// append bias_k/bias_v token at s=2048, zero rows 2049..2111
__global__ void fill_kv_pad(float* __restrict__ k_h, float* __restrict__ v_h,
                            const float* __restrict__ bias_k,
                            const float* __restrict__ bias_v)
{
    const int d   = threadIdx.x;            // 0..63
    const int row = S_DIM + blockIdx.x;     // 2048..2111
    const int n   = blockIdx.y;             // 0..63
    const float bk = (row == S_DIM) ? bias_k[(n & 15) * HD + d] : 0.0f;
    const float bv = (row == S_DIM) ? bias_v[(n & 15) * HD + d] : 0.0f;
    const size_t idx = ((size_t)n * SPAD + row) * HD + d;
    k_h[idx] = bk;
    v_h[idx] = bv;
}

// ---------------------------------------------------------------------------
// Flash attention (f32): per block = one (n, 32-query tile).
// 8 lanes per query row, each owning 8 key-columns / 8 d-columns.
// Stores O (unnormalized->normalized), and per-row m, l for the colsum pass.
// ---------------------------------------------------------------------------
__global__ __launch_bounds__(256)
void attn_k(const float* __restrict__ q_h, const float* __restrict__ k_h,
            const float* __restrict__ v_h, float* __restrict__ o_h,
            float* __restrict__ m_arr, float* __restrict__ l_arr)
{
    __shared__ float Qs[32][65];
    __shared__ float Ks[64][65];
    __shared__ float Vs[64][65];
    __shared__ float Ps[32][65];

    const int n  = blockIdx.y;
    const int q0 = blockIdx.x * 32;
    const int tid = threadIdx.x;
    const int qr  = tid >> 3;        // 0..31 query row
    const int oct = tid & 7;         // 0..7
    const int dbase = oct * 8;

    { // load Q tile: 32x64
        const int row = tid >> 3;
        const int cb  = (tid & 7) * 8;
        const float* src = q_h + ((size_t)n * T_DIM + q0 + row) * HD + cb;
        const float4 a = *reinterpret_cast<const float4*>(src);
        const float4 b = *reinterpret_cast<const float4*>(src + 4);
        Qs[row][cb + 0] = a.x; Qs[row][cb + 1] = a.y; Qs[row][cb + 2] = a.z; Qs[row][cb + 3] = a.w;
        Qs[row][cb + 4] = b.x; Qs[row][cb + 5] = b.y; Qs[row][cb + 6] = b.z; Qs[row][cb + 7] = b.w;
    }

    float mcur = -1e30f, lcur = 0.0f;
    float o[8] = {0.f, 0.f, 0.f, 0.f, 0.f, 0.f, 0.f, 0.f};

    for (int kc = 0; kc < NCHUNK; ++kc) {
        const int s0 = kc * 64;
        { // load K,V chunk 64x64 each
            const int row = tid >> 2;
            const int cb  = (tid & 3) * 16;
            const float* ks = k_h + ((size_t)n * SPAD + s0 + row) * HD + cb;
            const float* vs = v_h + ((size_t)n * SPAD + s0 + row) * HD + cb;
#pragma unroll
            for (int q = 0; q < 4; ++q) {
                const float4 kv = *reinterpret_cast<const float4*>(ks + q * 4);
                Ks[row][cb + q * 4 + 0] = kv.x; Ks[row][cb + q * 4 + 1] = kv.y;
                Ks[row][cb + q * 4 + 2] = kv.z; Ks[row][cb + q * 4 + 3] = kv.w;
                const float4 vv = *reinterpret_cast<const float4*>(vs + q * 4);
                Vs[row][cb + q * 4 + 0] = vv.x; Vs[row][cb + q * 4 + 1] = vv.y;
                Vs[row][cb + q * 4 + 2] = vv.z; Vs[row][cb + q * 4 + 3] = vv.w;
            }
        }
        __syncthreads();

        // scores: this lane's 8 keys
        float s[8] = {0.f, 0.f, 0.f, 0.f, 0.f, 0.f, 0.f, 0.f};
#pragma unroll 4
        for (int d = 0; d < HD; ++d) {
            const float qd = Qs[qr][d];
#pragma unroll
            for (int jj = 0; jj < 8; ++jj)
                s[jj] = fmaf(qd, Ks[oct * 8 + jj][d], s[jj]);
        }
#pragma unroll
        for (int jj = 0; jj < 8; ++jj)
            if (s0 + oct * 8 + jj >= SP1) s[jj] = -1e30f;

        float mx = s[0];
#pragma unroll
        for (int jj = 1; jj < 8; ++jj) mx = fmaxf(mx, s[jj]);
        mx = fmaxf(mx, __shfl_xor(mx, 1, 8));
        mx = fmaxf(mx, __shfl_xor(mx, 2, 8));
        mx = fmaxf(mx, __shfl_xor(mx, 4, 8));

        const float m_new = fmaxf(mcur, mx);
        float p[8];
        float psum = 0.f;
#pragma unroll
        for (int jj = 0; jj < 8; ++jj) { p[jj] = __expf(s[jj] - m_new); psum += p[jj]; }
        psum += __shfl_xor(psum, 1, 8);
        psum += __shfl_xor(psum, 2, 8);
        psum += __shfl_xor(psum, 4, 8);

        const float factor = __expf(mcur - m_new);
        lcur = lcur * factor + psum;
        mcur = m_new;
#pragma unroll
        for (int dd = 0; dd < 8; ++dd) o[dd] *= factor;
#pragma unroll
        for (int jj = 0; jj < 8; ++jj) Ps[qr][oct * 8 + jj] = p[jj];
        __syncthreads();

#pragma unroll 4
        for (int kk = 0; kk < 64; ++kk) {
            const float pv = Ps[qr][kk];
#pragma unroll
            for (int dd = 0; dd < 8; ++dd)
                o[dd] = fmaf(pv, Vs[kk][dbase + dd], o[dd]);
        }
        __syncthreads();
    }

    const float inv_l = 1.0f / lcur;
    float* dst = o_h + ((size_t)n * T_DIM + q0 + qr) * HD + dbase;
#pragma unroll
    for (int dd = 0; dd < 8; ++dd) dst[dd] = o[dd] * inv_l;

    if (oct == 0) {
        m_arr[n * T_DIM + q0 + qr] = mcur;
        l_arr[n * T_DIM + q0 + qr] = lcur;
    }
}

// ---------------------------------------------------------------------------
// avg_weights: block = (n, 64-key tile); loops over all q, recomputes
// w = exp(q.k - m)/l and accumulates column sums. Writes sum/H.
// ---------------------------------------------------------------------------
__global__ __launch_bounds__(256)
void colsum_k(const float* __restrict__ q_h, const float* __restrict__ k_h,
              const float* __restrict__ m_arr, const float* __restrict__ l_arr,
              float* __restrict__ avg_out)
{
    __shared__ float Ks[64][65];
    __shared__ float Qs[32][65];
    __shared__ float ms[32];
    __shared__ float li[32];
    __shared__ float red[4][64];

    const int n  = blockIdx.y;
    const int s0 = blockIdx.x * 64;
    const int tid = threadIdx.x;
    const int kl = tid & 63;
    const int qg = tid >> 6;

    { // load K tile once
        const int row = tid >> 2;
        const int cb  = (tid & 3) * 16;
        const float* src = k_h + ((size_t)n * SPAD + s0 + row) * HD + cb;
#pragma unroll
        for (int q = 0; q < 4; ++q) {
            const float4 kv = *reinterpret_cast<const float4*>(src + q * 4);
            Ks[row][cb + q * 4 + 0] = kv.x; Ks[row][cb + q * 4 + 1] = kv.y;
            Ks[row][cb + q * 4 + 2] = kv.z; Ks[row][cb + q * 4 + 3] = kv.w;
        }
    }

    float csum = 0.f;
    for (int q0 = 0; q0 < T_DIM; q0 += 32) {
        { // load Q tile 32x64
            const int row = tid >> 3;
            const int cb  = (tid & 7) * 8;
            const float* src = q_h + ((size_t)n * T_DIM + q0 + row) * HD + cb;
            const float4 a = *reinterpret_cast<const float4*>(src);
            const float4 b = *reinterpret_cast<const float4*>(src + 4);
            Qs[row][cb + 0] = a.x; Qs[row][cb + 1] = a.y; Qs[row][cb + 2] = a.z; Qs[row][cb + 3] = a.w;
            Qs[row][cb + 4] = b.x; Qs[row][cb + 5] = b.y; Qs[row][cb + 6] = b.z; Qs[row][cb + 7] = b.w;
        }
        if (tid < 32) {
            ms[tid] = m_arr[n * T_DIM + q0 + tid];
            li[tid] = 1.0f / l_arr[n * T_DIM + q0 + tid];
        }
        __syncthreads();

#pragma unroll
        for (int qi = 0; qi < 8; ++qi) {
            const int q = qg * 8 + qi;
            float s = 0.f;
#pragma unroll 8
            for (int d = 0; d < HD; ++d) s = fmaf(Qs[q][d], Ks[kl][d], s);
            csum += __expf(s - ms[q]) * li[q];
        }
        __syncthreads();
    }

    red[qg][kl] = csum;
    __syncthreads();
    if (tid < 64) {
        const float tot = red[0][tid] + red[1][tid] + red[2][tid] + red[3][tid];
        const int col = s0 + tid;
        if (col < SP1)
            avg_out[(size_t)n * SP1 + col] = tot * (1.0f / 16.0f);
    }
}

// ---------------------------------------------------------------------------
extern "C" void kernel_launch(void* const* d_in, const int* in_sizes, int n_in,
                              void* d_out, int out_size, void* d_ws, size_t ws_size,
                              hipStream_t stream)
{
    const float* query   = (const float*)d_in[0];
    const float* key     = (const float*)d_in[1];
    const float* value   = (const float*)d_in[2];
    const float* wq      = (const float*)d_in[3];
    const float* wk      = (const float*)d_in[4];
    const float* wv      = (const float*)d_in[5];
    const float* in_bias = (const float*)d_in[6];
    const float* bias_k  = (const float*)d_in[7];
    const float* bias_v  = (const float*)d_in[8];
    const float* wo      = (const float*)d_in[9];
    const float* out_b   = (const float*)d_in[10];
    float* out = (float*)d_out;

    float* q_h   = (float*)d_ws;                          // [64][2048][64]
    float* k_h   = q_h  + (size_t)NH * T_DIM * HD;        // [64][2112][64]
    float* v_h   = k_h  + (size_t)NH * SPAD * HD;         // [64][2112][64]
    float* attn  = v_h  + (size_t)NH * SPAD * HD;         // [64][2048][64]
    float* m_arr = attn + (size_t)NH * T_DIM * HD;        // [64][2048]
    float* l_arr = m_arr + (size_t)NH * T_DIM;            // [64][2048]

    const dim3 gg(128, 16), blk(256);
    hipLaunchKernelGGL((linear_k<0>), gg, blk, 0, stream, query, wq, in_bias, q_h);
    hipLaunchKernelGGL((linear_k<1>), gg, blk, 0, stream, key,   wk, in_bias + E_DIM, k_h);
    hipLaunchKernelGGL((linear_k<2>), gg, blk, 0, stream, value, wv, in_bias + 2 * E_DIM, v_h);
    hipLaunchKernelGGL(fill_kv_pad, dim3(SPAD - S_DIM, NH), dim3(64), 0, stream,
                       k_h, v_h, bias_k, bias_v);
    hipLaunchKernelGGL(attn_k, dim3(T_DIM / 32, NH), blk, 0, stream,
                       q_h, k_h, v_h, attn, m_arr, l_arr);
    hipLaunchKernelGGL(colsum_k, dim3(NCHUNK, NH), blk, 0, stream,
                       q_h, k_h, m_arr, l_arr, out + (size_t)T_DIM * B_DIM * E_DIM);
    hipLaunchKernelGGL((linear_k<3>), gg, blk, 0, stream, attn, wo, out_b, out);
}

// Round 2
// 449.054 us; speedup vs baseline: 15.0777x; 15.0777x over previous
//
#include <hip/hip_runtime.h>

#define T_DIM 2048
#define B_DIM 4
#define S_DIM 2048
#define E_DIM 1024
#define H_NUM 16
#define HD    64
#define NH    64      // B*H
#define SP1   2049    // S+1 (bias token appended)
#define SPAD  2112    // 33*64, padded key length
#define NCHUNK 33

typedef short bf16x8 __attribute__((ext_vector_type(8)));
typedef float f32x4  __attribute__((ext_vector_type(4)));

__device__ __forceinline__ unsigned short f2bf(float x) {
    union { float f; unsigned int u; } v; v.f = x;
    unsigned int r = v.u + 0x7FFFu + ((v.u >> 16) & 1u);   // RNE
    return (unsigned short)(r >> 16);
}

// ---------------------------------------------------------------------------
// f32 -> bf16 bulk convert, 8 elems/thread
// ---------------------------------------------------------------------------
__global__ __launch_bounds__(256)
void cvt_bf16_k(const float* __restrict__ src, short* __restrict__ dst, int n8)
{
    int i = blockIdx.x * 256 + threadIdx.x;
    if (i >= n8) return;
    const float4* s = reinterpret_cast<const float4*>(src) + (size_t)i * 2;
    float4 a = s[0], b = s[1];
    bf16x8 o;
    o[0] = (short)f2bf(a.x); o[1] = (short)f2bf(a.y);
    o[2] = (short)f2bf(a.z); o[3] = (short)f2bf(a.w);
    o[4] = (short)f2bf(b.x); o[5] = (short)f2bf(b.y);
    o[6] = (short)f2bf(b.z); o[7] = (short)f2bf(b.w);
    *(reinterpret_cast<bf16x8*>(dst) + i) = o;
}

// ---------------------------------------------------------------------------
// bf16 MFMA GEMM: C[m][n] = sum_k A[m][k] * W[n][k] + bias[n]
// BM=BN=128, BK=64, 256 threads = 4 waves (2x2), each wave 64x64 out.
// MODE 0: Q proj  -> (acc+b)*0.125 -> bf16 scatter q_h [n][T][64]
// MODE 1: K proj  -> bf16 scatter k_h [n][SPAD][64]
// MODE 2: V proj  -> bf16 scatter v_h [n][SPAD][64]
// MODE 3: out proj-> A gathered from o_h [n][T][64]; f32 out [8192][1024]
// ---------------------------------------------------------------------------
template<int MODE>
__global__ __launch_bounds__(256)
void gemm_bf16(const short* __restrict__ A, const short* __restrict__ W,
               const float* __restrict__ bias, void* __restrict__ outp)
{
    __shared__ short As[128][72];
    __shared__ short Bs[128][72];
    const int bm = blockIdx.x, bn = blockIdx.y;
    const int tid = threadIdx.x;
    const int l = tid & 63, w = tid >> 6;
    const int wr = w >> 1, wc = w & 1;
    const int lr = l & 15, lg = l >> 4;

    f32x4 acc[4][4] = {};

    for (int k0 = 0; k0 < E_DIM; k0 += 64) {
#pragma unroll
        for (int it = 0; it < 4; ++it) {
            const int idx = it * 256 + tid;
            const int row = idx >> 3, cg = idx & 7;
            size_t asrc;
            if (MODE == 3) {
                const int m = bm * 128 + row;
                asrc = ((size_t)((m & 3) * 16 + (k0 >> 6)) * T_DIM + (m >> 2)) * HD + cg * 8;
            } else {
                asrc = (size_t)(bm * 128 + row) * E_DIM + k0 + cg * 8;
            }
            *reinterpret_cast<bf16x8*>(&As[row][cg * 8]) =
                *reinterpret_cast<const bf16x8*>(A + asrc);
            *reinterpret_cast<bf16x8*>(&Bs[row][cg * 8]) =
                *reinterpret_cast<const bf16x8*>(W + (size_t)(bn * 128 + row) * E_DIM + k0 + cg * 8);
        }
        __syncthreads();
#pragma unroll
        for (int c = 0; c < 2; ++c) {
            bf16x8 af[4], bf[4];
#pragma unroll
            for (int mi = 0; mi < 4; ++mi)
                af[mi] = *reinterpret_cast<const bf16x8*>(&As[wr * 64 + mi * 16 + lr][c * 32 + lg * 8]);
#pragma unroll
            for (int ni = 0; ni < 4; ++ni)
                bf[ni] = *reinterpret_cast<const bf16x8*>(&Bs[wc * 64 + ni * 16 + lr][c * 32 + lg * 8]);
#pragma unroll
            for (int mi = 0; mi < 4; ++mi)
#pragma unroll
                for (int ni = 0; ni < 4; ++ni)
                    acc[mi][ni] = __builtin_amdgcn_mfma_f32_16x16x32_bf16(
                        af[mi], bf[ni], acc[mi][ni], 0, 0, 0);
        }
        __syncthreads();
    }

#pragma unroll
    for (int mi = 0; mi < 4; ++mi)
#pragma unroll
        for (int ni = 0; ni < 4; ++ni) {
            const int colg = bn * 128 + wc * 64 + ni * 16 + lr;
            const float bv = bias[colg];
#pragma unroll
            for (int r = 0; r < 4; ++r) {
                const int m = bm * 128 + wr * 64 + mi * 16 + lg * 4 + r;
                float v = acc[mi][ni][r] + bv;
                if (MODE == 3) {
                    ((float*)outp)[(size_t)m * E_DIM + colg] = v;
                } else {
                    if (MODE == 0) v *= 0.125f;
                    const int seq = m >> 2, b = m & 3;
                    const int head = colg >> 6, d = colg & 63;
                    const int sd = (MODE == 0) ? T_DIM : SPAD;
                    ((short*)outp)[((size_t)(b * 16 + head) * sd + seq) * HD + d] = (short)f2bf(v);
                }
            }
        }
}

// append bias_k/bias_v token at s=2048 (bf16), zero rows 2049..2111
__global__ void fill_kv_pad(short* __restrict__ k_h, short* __restrict__ v_h,
                            const float* __restrict__ bias_k,
                            const float* __restrict__ bias_v)
{
    const int d   = threadIdx.x;            // 0..63
    const int row = S_DIM + blockIdx.x;     // 2048..2111
    const int n   = blockIdx.y;             // 0..63
    short bk = 0, bv = 0;
    if (row == S_DIM) {
        bk = (short)f2bf(bias_k[(n & 15) * HD + d]);
        bv = (short)f2bf(bias_v[(n & 15) * HD + d]);
    }
    const size_t idx = ((size_t)n * SPAD + row) * HD + d;
    k_h[idx] = bk;
    v_h[idx] = bv;
}

// ---------------------------------------------------------------------------
// MFMA flash attention: block = (n, 64 q-rows); wave w owns 16 q-rows.
// 64-key chunks: QK^T (MFMA) -> online softmax (width-16 butterflies) ->
// P via LDS bf16 -> PV (MFMA vs transposed V in LDS).
// ---------------------------------------------------------------------------
__global__ __launch_bounds__(256)
void attn_mfma(const short* __restrict__ q_h, const short* __restrict__ k_h,
               const short* __restrict__ v_h, short* __restrict__ o_h,
               float* __restrict__ m_arr, float* __restrict__ l_arr)
{
    __shared__ short Ks[64][72];
    __shared__ short Vt[64][72];       // Vt[d][key]
    __shared__ short Ps[4][16][72];    // per-wave P tile

    const int n = blockIdx.y, q0 = blockIdx.x * 64;
    const int tid = threadIdx.x, l = tid & 63, w = tid >> 6;
    const int lr = l & 15, lg = l >> 4;

    bf16x8 aq[2];
#pragma unroll
    for (int c = 0; c < 2; ++c)
        aq[c] = *reinterpret_cast<const bf16x8*>(
            q_h + ((size_t)n * T_DIM + q0 + w * 16 + lr) * HD + c * 32 + lg * 8);

    float m_run[4] = {-1e30f, -1e30f, -1e30f, -1e30f};
    float l_run[4] = {0.f, 0.f, 0.f, 0.f};
    f32x4 acc_o[4] = {};

    for (int kc = 0; kc < NCHUNK; ++kc) {
        const int s0 = kc * 64;
        // stage K row-major
#pragma unroll
        for (int it = 0; it < 2; ++it) {
            const int idx = it * 256 + tid;
            const int row = idx >> 3, cg = idx & 7;
            *reinterpret_cast<bf16x8*>(&Ks[row][cg * 8]) =
                *reinterpret_cast<const bf16x8*>(k_h + ((size_t)n * SPAD + s0 + row) * HD + cg * 8);
        }
        // stage V transposed (packed u32 column-pair writes)
        {
            const int sp = tid & 31, d0 = (tid >> 5) * 8;
            const short* v0 = v_h + ((size_t)n * SPAD + s0 + 2 * sp) * HD + d0;
            bf16x8 va = *reinterpret_cast<const bf16x8*>(v0);
            bf16x8 vb = *reinterpret_cast<const bf16x8*>(v0 + HD);
#pragma unroll
            for (int j = 0; j < 8; ++j) {
                unsigned int pk = (unsigned int)(unsigned short)va[j]
                                | ((unsigned int)(unsigned short)vb[j] << 16);
                *reinterpret_cast<unsigned int*>(&Vt[d0 + j][2 * sp]) = pk;
            }
        }
        __syncthreads();

        // QK^T: S[16 q][64 keys]
        f32x4 sc[4];
#pragma unroll
        for (int kt = 0; kt < 4; ++kt) {
            bf16x8 bk0 = *reinterpret_cast<const bf16x8*>(&Ks[kt * 16 + lr][lg * 8]);
            bf16x8 bk1 = *reinterpret_cast<const bf16x8*>(&Ks[kt * 16 + lr][32 + lg * 8]);
            f32x4 z = {0.f, 0.f, 0.f, 0.f};
            z = __builtin_amdgcn_mfma_f32_16x16x32_bf16(aq[0], bk0, z, 0, 0, 0);
            sc[kt] = __builtin_amdgcn_mfma_f32_16x16x32_bf16(aq[1], bk1, z, 0, 0, 0);
        }
        if (s0 + 64 > SP1) {   // only the final chunk has invalid keys
#pragma unroll
            for (int kt = 0; kt < 4; ++kt)
                if (s0 + kt * 16 + lr >= SP1) {
                    sc[kt][0] = -1e30f; sc[kt][1] = -1e30f;
                    sc[kt][2] = -1e30f; sc[kt][3] = -1e30f;
                }
        }

        // online softmax; lane holds rows lg*4+r, cols kt*16+lr
        float p[4][4];
#pragma unroll
        for (int r = 0; r < 4; ++r) {
            float mx = fmaxf(fmaxf(sc[0][r], sc[1][r]), fmaxf(sc[2][r], sc[3][r]));
            mx = fmaxf(mx, __shfl_xor(mx, 1, 16));
            mx = fmaxf(mx, __shfl_xor(mx, 2, 16));
            mx = fmaxf(mx, __shfl_xor(mx, 4, 16));
            mx = fmaxf(mx, __shfl_xor(mx, 8, 16));
            const float mnew = fmaxf(m_run[r], mx);
            const float fac = __expf(m_run[r] - mnew);
            float ps = 0.f;
#pragma unroll
            for (int kt = 0; kt < 4; ++kt) { p[kt][r] = __expf(sc[kt][r] - mnew); ps += p[kt][r]; }
            ps += __shfl_xor(ps, 1, 16);
            ps += __shfl_xor(ps, 2, 16);
            ps += __shfl_xor(ps, 4, 16);
            ps += __shfl_xor(ps, 8, 16);
            l_run[r] = l_run[r] * fac + ps;
            m_run[r] = mnew;
#pragma unroll
            for (int dt = 0; dt < 4; ++dt) acc_o[dt][r] *= fac;
        }

        // P -> LDS bf16 (per-wave region; same-wave RAW, no barrier needed)
#pragma unroll
        for (int kt = 0; kt < 4; ++kt)
#pragma unroll
            for (int r = 0; r < 4; ++r)
                Ps[w][lg * 4 + r][kt * 16 + lr] = (short)f2bf(p[kt][r]);

        // PV: O += P @ V
#pragma unroll
        for (int ks = 0; ks < 2; ++ks) {
            bf16x8 ap = *reinterpret_cast<const bf16x8*>(&Ps[w][lr][ks * 32 + lg * 8]);
#pragma unroll
            for (int dt = 0; dt < 4; ++dt) {
                bf16x8 bv = *reinterpret_cast<const bf16x8*>(&Vt[dt * 16 + lr][ks * 32 + lg * 8]);
                acc_o[dt] = __builtin_amdgcn_mfma_f32_16x16x32_bf16(ap, bv, acc_o[dt], 0, 0, 0);
            }
        }
        __syncthreads();
    }

    float il[4];
#pragma unroll
    for (int r = 0; r < 4; ++r) il[r] = 1.0f / l_run[r];
#pragma unroll
    for (int dt = 0; dt < 4; ++dt)
#pragma unroll
        for (int r = 0; r < 4; ++r) {
            const int row = q0 + w * 16 + lg * 4 + r;
            o_h[((size_t)n * T_DIM + row) * HD + dt * 16 + lr] =
                (short)f2bf(acc_o[dt][r] * il[r]);
        }
    if (lr == 0) {
#pragma unroll
        for (int r = 0; r < 4; ++r) {
            const int row = q0 + w * 16 + lg * 4 + r;
            m_arr[n * T_DIM + row] = m_run[r];
            l_arr[n * T_DIM + row] = l_run[r];
        }
    }
}

// ---------------------------------------------------------------------------
// avg_weights via MFMA: block = (n, 64 keys); wave w owns 16 keys.
// S^T = K @ Q^T per 16-q tile; csum += exp(s - m_q)/l_q; butterfly-reduce.
// ---------------------------------------------------------------------------
__global__ __launch_bounds__(256)
void colsum_mfma(const short* __restrict__ q_h, const short* __restrict__ k_h,
                 const float* __restrict__ m_arr, const float* __restrict__ l_arr,
                 float* __restrict__ avg_out)
{
    __shared__ short Qs[64][72];
    __shared__ float ms[64];
    __shared__ float li[64];

    const int n = blockIdx.y, s0 = blockIdx.x * 64;
    const int tid = threadIdx.x, l = tid & 63, w = tid >> 6;
    const int lr = l & 15, lg = l >> 4;

    bf16x8 ak[2];
#pragma unroll
    for (int c = 0; c < 2; ++c)
        ak[c] = *reinterpret_cast<const bf16x8*>(
            k_h + ((size_t)n * SPAD + s0 + w * 16 + lr) * HD + c * 32 + lg * 8);

    float csum[4] = {0.f, 0.f, 0.f, 0.f};

    for (int qo = 0; qo < T_DIM; qo += 64) {
#pragma unroll
        for (int it = 0; it < 2; ++it) {
            const int idx = it * 256 + tid;
            const int row = idx >> 3, cg = idx & 7;
            *reinterpret_cast<bf16x8*>(&Qs[row][cg * 8]) =
                *reinterpret_cast<const bf16x8*>(q_h + ((size_t)n * T_DIM + qo + row) * HD + cg * 8);
        }
        if (tid < 64) ms[tid] = m_arr[n * T_DIM + qo + tid];
        else if (tid < 128) li[tid - 64] = 1.0f / l_arr[n * T_DIM + qo + tid - 64];
        __syncthreads();
#pragma unroll
        for (int qt = 0; qt < 4; ++qt) {
            bf16x8 bq0 = *reinterpret_cast<const bf16x8*>(&Qs[qt * 16 + lr][lg * 8]);
            bf16x8 bq1 = *reinterpret_cast<const bf16x8*>(&Qs[qt * 16 + lr][32 + lg * 8]);
            f32x4 z = {0.f, 0.f, 0.f, 0.f};
            z = __builtin_amdgcn_mfma_f32_16x16x32_bf16(ak[0], bq0, z, 0, 0, 0);
            z = __builtin_amdgcn_mfma_f32_16x16x32_bf16(ak[1], bq1, z, 0, 0, 0);
            const float mq = ms[qt * 16 + lr];
            const float lq = li[qt * 16 + lr];
#pragma unroll
            for (int r = 0; r < 4; ++r)
                csum[r] += __expf(z[r] - mq) * lq;
        }
        __syncthreads();
    }
#pragma unroll
    for (int r = 0; r < 4; ++r) {
        float v = csum[r];
        v += __shfl_xor(v, 1, 16);
        v += __shfl_xor(v, 2, 16);
        v += __shfl_xor(v, 4, 16);
        v += __shfl_xor(v, 8, 16);
        if (lr == 0) {
            const int key = s0 + w * 16 + lg * 4 + r;
            if (key < SP1) avg_out[(size_t)n * SP1 + key] = v * 0.0625f;
        }
    }
}

// ---------------------------------------------------------------------------
extern "C" void kernel_launch(void* const* d_in, const int* in_sizes, int n_in,
                              void* d_out, int out_size, void* d_ws, size_t ws_size,
                              hipStream_t stream)
{
    const float* query   = (const float*)d_in[0];
    const float* key     = (const float*)d_in[1];
    const float* value   = (const float*)d_in[2];
    const float* wq      = (const float*)d_in[3];
    const float* wk      = (const float*)d_in[4];
    const float* wv      = (const float*)d_in[5];
    const float* in_bias = (const float*)d_in[6];
    const float* bias_k  = (const float*)d_in[7];
    const float* bias_v  = (const float*)d_in[8];
    const float* wo      = (const float*)d_in[9];
    const float* out_b   = (const float*)d_in[10];
    float* out = (float*)d_out;

    const size_t NTOK = (size_t)T_DIM * B_DIM;           // 8192
    short* qx  = (short*)d_ws;                           // [8192][1024] bf16
    short* kx  = qx  + NTOK * E_DIM;
    short* vx  = kx  + NTOK * E_DIM;
    short* wqb = vx  + NTOK * E_DIM;                     // [1024][1024] bf16 x4
    short* wkb = wqb + (size_t)E_DIM * E_DIM;
    short* wvb = wkb + (size_t)E_DIM * E_DIM;
    short* wob = wvb + (size_t)E_DIM * E_DIM;
    short* q_h = wob + (size_t)E_DIM * E_DIM;            // [64][2048][64]
    short* k_h = q_h + (size_t)NH * T_DIM * HD;          // [64][2112][64]
    short* v_h = k_h + (size_t)NH * SPAD * HD;           // [64][2112][64]
    short* o_h = v_h + (size_t)NH * SPAD * HD;           // [64][2048][64]
    float* m_arr = (float*)(o_h + (size_t)NH * T_DIM * HD);
    float* l_arr = m_arr + (size_t)NH * T_DIM;

    const int n8_x = (int)(NTOK * E_DIM / 8);            // 1,048,576
    const int n8_w = E_DIM * E_DIM / 8;                  // 131,072
    const dim3 blk(256);
    hipLaunchKernelGGL(cvt_bf16_k, dim3((n8_x + 255) / 256), blk, 0, stream, query, qx, n8_x);
    hipLaunchKernelGGL(cvt_bf16_k, dim3((n8_x + 255) / 256), blk, 0, stream, key,   kx, n8_x);
    hipLaunchKernelGGL(cvt_bf16_k, dim3((n8_x + 255) / 256), blk, 0, stream, value, vx, n8_x);
    hipLaunchKernelGGL(cvt_bf16_k, dim3((n8_w + 255) / 256), blk, 0, stream, wq, wqb, n8_w);
    hipLaunchKernelGGL(cvt_bf16_k, dim3((n8_w + 255) / 256), blk, 0, stream, wk, wkb, n8_w);
    hipLaunchKernelGGL(cvt_bf16_k, dim3((n8_w + 255) / 256), blk, 0, stream, wv, wvb, n8_w);
    hipLaunchKernelGGL(cvt_bf16_k, dim3((n8_w + 255) / 256), blk, 0, stream, wo, wob, n8_w);

    const dim3 gg(64, 8);
    hipLaunchKernelGGL((gemm_bf16<0>), gg, blk, 0, stream, qx, wqb, in_bias,             (void*)q_h);
    hipLaunchKernelGGL((gemm_bf16<1>), gg, blk, 0, stream, kx, wkb, in_bias + E_DIM,     (void*)k_h);
    hipLaunchKernelGGL((gemm_bf16<2>), gg, blk, 0, stream, vx, wvb, in_bias + 2 * E_DIM, (void*)v_h);
    hipLaunchKernelGGL(fill_kv_pad, dim3(SPAD - S_DIM, NH), dim3(64), 0, stream,
                       k_h, v_h, bias_k, bias_v);
    hipLaunchKernelGGL(attn_mfma, dim3(T_DIM / 64, NH), blk, 0, stream,
                       q_h, k_h, v_h, o_h, m_arr, l_arr);
    hipLaunchKernelGGL(colsum_mfma, dim3(NCHUNK, NH), blk, 0, stream,
                       q_h, k_h, m_arr, l_arr, out + (size_t)T_DIM * B_DIM * E_DIM);
    hipLaunchKernelGGL((gemm_bf16<3>), gg, blk, 0, stream, o_h, wob, out_b, (void*)out);
}

// Round 3
// 333.866 us; speedup vs baseline: 20.2797x; 1.3450x over previous
//
#include <hip/hip_runtime.h>

#define T_DIM 2048
#define B_DIM 4
#define S_DIM 2048
#define E_DIM 1024
#define H_NUM 16
#define HD    64
#define NH    64      // B*H
#define SP1   2049    // S+1 (bias token appended)
#define SPAD  2112    // 33*64, padded key length
#define NCHUNK 33

typedef short bf16x8 __attribute__((ext_vector_type(8)));
typedef float f32x4  __attribute__((ext_vector_type(4)));
typedef float f32x16 __attribute__((ext_vector_type(16)));
typedef unsigned int u32;

// log2(e): softmax done in exp2 domain; folded into Q projection scale.
#define QSCALE 0.18033688011112042f   // 0.125 * log2(e)

#if __has_builtin(__builtin_amdgcn_exp2f)
__device__ __forceinline__ float exp2_fast(float x) { return __builtin_amdgcn_exp2f(x); }
#else
__device__ __forceinline__ float exp2_fast(float x) { return __expf(x * 0.6931471805599453f); }
#endif

__device__ __forceinline__ unsigned short f2bf(float x) {
    union { float f; unsigned int u; } v; v.f = x;
    unsigned int r = v.u + 0x7FFFu + ((v.u >> 16) & 1u);   // RNE
    return (unsigned short)(r >> 16);
}

__device__ __forceinline__ u32 cvtpk_bf16(float lo, float hi) {
    u32 r;
    asm("v_cvt_pk_bf16_f32 %0, %1, %2" : "=v"(r) : "v"(lo), "v"(hi));
    return r;
}
// swaps upper 32 lanes of a with lower 32 lanes of b
__device__ __forceinline__ void plswap(u32& a, u32& b) {
    asm("v_permlane32_swap_b32 %0, %1" : "+v"(a), "+v"(b));
}

// ---------------------------------------------------------------------------
// f32 -> bf16 bulk convert, 8 elems/thread
// ---------------------------------------------------------------------------
__global__ __launch_bounds__(256)
void cvt_bf16_k(const float* __restrict__ src, short* __restrict__ dst, int n8)
{
    int i = blockIdx.x * 256 + threadIdx.x;
    if (i >= n8) return;
    const float4* s = reinterpret_cast<const float4*>(src) + (size_t)i * 2;
    float4 a = s[0], b = s[1];
    bf16x8 o;
    o[0] = (short)f2bf(a.x); o[1] = (short)f2bf(a.y);
    o[2] = (short)f2bf(a.z); o[3] = (short)f2bf(a.w);
    o[4] = (short)f2bf(b.x); o[5] = (short)f2bf(b.y);
    o[6] = (short)f2bf(b.z); o[7] = (short)f2bf(b.w);
    *(reinterpret_cast<bf16x8*>(dst) + i) = o;
}

// ---------------------------------------------------------------------------
// bf16 MFMA GEMM (unchanged structure from round 2)
// ---------------------------------------------------------------------------
template<int MODE>
__global__ __launch_bounds__(256)
void gemm_bf16(const short* __restrict__ A, const short* __restrict__ W,
               const float* __restrict__ bias, void* __restrict__ outp)
{
    __shared__ short As[128][72];
    __shared__ short Bs[128][72];
    const int bm = blockIdx.x, bn = blockIdx.y;
    const int tid = threadIdx.x;
    const int l = tid & 63, w = tid >> 6;
    const int wr = w >> 1, wc = w & 1;
    const int lr = l & 15, lg = l >> 4;

    f32x4 acc[4][4] = {};

    for (int k0 = 0; k0 < E_DIM; k0 += 64) {
#pragma unroll
        for (int it = 0; it < 4; ++it) {
            const int idx = it * 256 + tid;
            const int row = idx >> 3, cg = idx & 7;
            size_t asrc;
            if (MODE == 3) {
                const int m = bm * 128 + row;
                asrc = ((size_t)((m & 3) * 16 + (k0 >> 6)) * T_DIM + (m >> 2)) * HD + cg * 8;
            } else {
                asrc = (size_t)(bm * 128 + row) * E_DIM + k0 + cg * 8;
            }
            *reinterpret_cast<bf16x8*>(&As[row][cg * 8]) =
                *reinterpret_cast<const bf16x8*>(A + asrc);
            *reinterpret_cast<bf16x8*>(&Bs[row][cg * 8]) =
                *reinterpret_cast<const bf16x8*>(W + (size_t)(bn * 128 + row) * E_DIM + k0 + cg * 8);
        }
        __syncthreads();
#pragma unroll
        for (int c = 0; c < 2; ++c) {
            bf16x8 af[4], bf[4];
#pragma unroll
            for (int mi = 0; mi < 4; ++mi)
                af[mi] = *reinterpret_cast<const bf16x8*>(&As[wr * 64 + mi * 16 + lr][c * 32 + lg * 8]);
#pragma unroll
            for (int ni = 0; ni < 4; ++ni)
                bf[ni] = *reinterpret_cast<const bf16x8*>(&Bs[wc * 64 + ni * 16 + lr][c * 32 + lg * 8]);
#pragma unroll
            for (int mi = 0; mi < 4; ++mi)
#pragma unroll
                for (int ni = 0; ni < 4; ++ni)
                    acc[mi][ni] = __builtin_amdgcn_mfma_f32_16x16x32_bf16(
                        af[mi], bf[ni], acc[mi][ni], 0, 0, 0);
        }
        __syncthreads();
    }

#pragma unroll
    for (int mi = 0; mi < 4; ++mi)
#pragma unroll
        for (int ni = 0; ni < 4; ++ni) {
            const int colg = bn * 128 + wc * 64 + ni * 16 + lr;
            const float bv = bias[colg];
#pragma unroll
            for (int r = 0; r < 4; ++r) {
                const int m = bm * 128 + wr * 64 + mi * 16 + lg * 4 + r;
                float v = acc[mi][ni][r] + bv;
                if (MODE == 3) {
                    ((float*)outp)[(size_t)m * E_DIM + colg] = v;
                } else {
                    if (MODE == 0) v *= QSCALE;
                    const int seq = m >> 2, b = m & 3;
                    const int head = colg >> 6, d = colg & 63;
                    const int sd = (MODE == 0) ? T_DIM : SPAD;
                    ((short*)outp)[((size_t)(b * 16 + head) * sd + seq) * HD + d] = (short)f2bf(v);
                }
            }
        }
}

// append bias_k/bias_v token at s=2048 (bf16), zero rows 2049..2111
__global__ void fill_kv_pad(short* __restrict__ k_h, short* __restrict__ v_h,
                            const float* __restrict__ bias_k,
                            const float* __restrict__ bias_v)
{
    const int d   = threadIdx.x;
    const int row = S_DIM + blockIdx.x;
    const int n   = blockIdx.y;
    short bk = 0, bv = 0;
    if (row == S_DIM) {
        bk = (short)f2bf(bias_k[(n & 15) * HD + d]);
        bv = (short)f2bf(bias_v[(n & 15) * HD + d]);
    }
    const size_t idx = ((size_t)n * SPAD + row) * HD + d;
    k_h[idx] = bk;
    v_h[idx] = bv;
}

// ---------------------------------------------------------------------------
// Swapped 32x32 MFMA flash attention (m214-style).
// Block = (n, 128 q-rows), 4 waves x 32 q. Lane's q = lane&31 for everything:
//   S^T = mfma32(K, Q): lane holds 32 scores (16 regs x 2 key-tiles) for q.
//   softmax: local max + one shfl_xor(32). Defer-max THR=8 (exp2 domain).
//   P fragment in-register via cvt_pk_bf16 + permlane32_swap.
//   O^T = mfma32(Vt, P): accumulator col = q -> scalar rescale.
// K and Vt in LDS, [64][64] bf16, XOR-swizzled (byte ^= (row&7)<<4).
// ---------------------------------------------------------------------------
__global__ __launch_bounds__(256)
void attn_mfma(const short* __restrict__ q_h, const short* __restrict__ k_h,
               const short* __restrict__ v_h, short* __restrict__ o_h,
               float* __restrict__ m_arr, float* __restrict__ l_arr)
{
    __shared__ short Ks[64 * 64];
    __shared__ short Vt[64 * 64];
    char* KsB = (char*)Ks;
    char* VtB = (char*)Vt;

    const int n = blockIdx.y, q0 = blockIdx.x * 128;
    const int tid = threadIdx.x, l = tid & 63, w = tid >> 6;
    const int ql = l & 31;
    const int hi = l >> 5;
    const int qrow = q0 + w * 32 + ql;

    // Q fragments: B[col=q][k]: lane holds q=ql, k = sl*16 + hi*8 + j
    bf16x8 aq0, aq1, aq2, aq3;
    {
        const short* qp = q_h + ((size_t)n * T_DIM + qrow) * HD + hi * 8;
        aq0 = *(const bf16x8*)(qp);
        aq1 = *(const bf16x8*)(qp + 16);
        aq2 = *(const bf16x8*)(qp + 32);
        aq3 = *(const bf16x8*)(qp + 48);
    }

    float m_run = -1e30f, l_run = 0.f;
    f32x16 accA, accB;
#pragma unroll
    for (int r = 0; r < 16; ++r) { accA[r] = 0.f; accB[r] = 0.f; }

    for (int kc = 0; kc < NCHUNK; ++kc) {
        const int s0 = kc * 64;
        // ---- stage K (row-major, swizzled) ----
#pragma unroll
        for (int it = 0; it < 2; ++it) {
            const int idx = it * 256 + tid;
            const int row = idx >> 3, cg = idx & 7;
            bf16x8 kv = *(const bf16x8*)(k_h + ((size_t)n * SPAD + s0 + row) * HD + cg * 8);
            *(bf16x8*)(KsB + row * 128 + ((cg * 16) ^ ((row & 7) << 4))) = kv;
        }
        // ---- stage V transposed (Vt[d][key], swizzled) ----
        {
            const int sp = tid & 31, d0 = (tid >> 5) * 8;
            const short* vp = v_h + ((size_t)n * SPAD + s0 + 2 * sp) * HD + d0;
            bf16x8 va = *(const bf16x8*)(vp);
            bf16x8 vb = *(const bf16x8*)(vp + HD);
#pragma unroll
            for (int j = 0; j < 8; ++j) {
                u32 pk = (u32)(unsigned short)va[j] | ((u32)(unsigned short)vb[j] << 16);
                const int d = d0 + j;
                *(u32*)(VtB + d * 128 + ((4 * sp) ^ ((d & 7) << 4))) = pk;
            }
        }
        __syncthreads();

        // ---- QK^T: S^T tiles (keys 0-31, 32-63), lane col = q ----
        f32x16 sc0, sc1;
#pragma unroll
        for (int r = 0; r < 16; ++r) { sc0[r] = 0.f; sc1[r] = 0.f; }
        const int coff = (hi * 16) ^ ((ql & 7) << 4);
#pragma unroll
        for (int sl = 0; sl < 4; ++sl) {
            bf16x8 kf0 = *(const bf16x8*)(KsB + ql * 128        + ((sl * 32) ^ coff ^ 0) + (coff & 16 ? 0 : 0));
            bf16x8 kf1 = *(const bf16x8*)(KsB + (32 + ql) * 128 + (((sl * 32) + hi * 16) ^ ((ql & 7) << 4)));
            kf0 = *(const bf16x8*)(KsB + ql * 128 + (((sl * 32) + hi * 16) ^ ((ql & 7) << 4)));
            bf16x8 qf = (sl == 0) ? aq0 : (sl == 1) ? aq1 : (sl == 2) ? aq2 : aq3;
            sc0 = __builtin_amdgcn_mfma_f32_32x32x16_bf16(kf0, qf, sc0, 0, 0, 0);
            sc1 = __builtin_amdgcn_mfma_f32_32x32x16_bf16(kf1, qf, sc1, 0, 0, 0);
        }

        // ---- mask invalid keys (last chunk only) ----
        if (s0 + 64 > SP1) {
#pragma unroll
            for (int r = 0; r < 16; ++r) {
                const int key = (r & 3) + 8 * (r >> 2) + 4 * hi;
                if (s0 + key >= SP1)      sc0[r] = -1e30f;
                if (s0 + 32 + key >= SP1) sc1[r] = -1e30f;
            }
        }

        // ---- online softmax (exp2 domain), defer-max THR=8 ----
        float mx = sc0[0];
#pragma unroll
        for (int r = 1; r < 16; ++r) mx = fmaxf(mx, sc0[r]);
#pragma unroll
        for (int r = 0; r < 16; ++r) mx = fmaxf(mx, sc1[r]);
        mx = fmaxf(mx, __shfl_xor(mx, 32));
        if (!__all(mx - m_run <= 8.0f)) {
            const float mnew = fmaxf(m_run, mx);
            const float fac = exp2_fast(m_run - mnew);
            l_run *= fac;
#pragma unroll
            for (int r = 0; r < 16; ++r) { accA[r] *= fac; accB[r] *= fac; }
            m_run = mnew;
        }
        float ps = 0.f;
        float p0[16], p1[16];
#pragma unroll
        for (int r = 0; r < 16; ++r) { p0[r] = exp2_fast(sc0[r] - m_run); ps += p0[r]; }
#pragma unroll
        for (int r = 0; r < 16; ++r) { p1[r] = exp2_fast(sc1[r] - m_run); ps += p1[r]; }
        ps += __shfl_xor(ps, 32);
        l_run += ps;

        // ---- P fragments: B[col=q][k], keys ksl*16 + hi*8 + j ----
        union PF { u32 u[4]; bf16x8 v; };
        PF pf0, pf1, pf2, pf3;
        {
            u32 a0 = cvtpk_bf16(p0[0], p0[1]),   b0 = cvtpk_bf16(p0[4], p0[5]);   plswap(a0, b0);
            u32 a1 = cvtpk_bf16(p0[2], p0[3]),   b1 = cvtpk_bf16(p0[6], p0[7]);   plswap(a1, b1);
            u32 a2 = cvtpk_bf16(p0[8], p0[9]),   b2 = cvtpk_bf16(p0[12], p0[13]); plswap(a2, b2);
            u32 a3 = cvtpk_bf16(p0[10], p0[11]), b3 = cvtpk_bf16(p0[14], p0[15]); plswap(a3, b3);
            pf0.u[0] = a0; pf0.u[1] = a1; pf0.u[2] = b0; pf0.u[3] = b1;
            pf1.u[0] = a2; pf1.u[1] = a3; pf1.u[2] = b2; pf1.u[3] = b3;
            u32 c0 = cvtpk_bf16(p1[0], p1[1]),   d0 = cvtpk_bf16(p1[4], p1[5]);   plswap(c0, d0);
            u32 c1 = cvtpk_bf16(p1[2], p1[3]),   d1 = cvtpk_bf16(p1[6], p1[7]);   plswap(c1, d1);
            u32 c2 = cvtpk_bf16(p1[8], p1[9]),   d2 = cvtpk_bf16(p1[12], p1[13]); plswap(c2, d2);
            u32 c3 = cvtpk_bf16(p1[10], p1[11]), d3 = cvtpk_bf16(p1[14], p1[15]); plswap(c3, d3);
            pf2.u[0] = c0; pf2.u[1] = c1; pf2.u[2] = d0; pf2.u[3] = d1;
            pf3.u[0] = c2; pf3.u[1] = c3; pf3.u[2] = d2; pf3.u[3] = d3;
        }

        // ---- PV: O^T += Vt @ P, d-tiles 0-31 / 32-63 ----
#pragma unroll
        for (int ksl = 0; ksl < 4; ++ksl) {
            const int cb = ((ksl * 32) + hi * 16) ^ ((ql & 7) << 4);
            bf16x8 vf0 = *(const bf16x8*)(VtB + ql * 128 + cb);
            bf16x8 vf1 = *(const bf16x8*)(VtB + (32 + ql) * 128 + cb);
            const bf16x8 pv = (ksl == 0) ? pf0.v : (ksl == 1) ? pf1.v : (ksl == 2) ? pf2.v : pf3.v;
            accA = __builtin_amdgcn_mfma_f32_32x32x16_bf16(vf0, pv, accA, 0, 0, 0);
            accB = __builtin_amdgcn_mfma_f32_32x32x16_bf16(vf1, pv, accB, 0, 0, 0);
        }
        __syncthreads();
    }

    // ---- epilogue: normalize, write O (lane q = ql), d = tile + (r&3)+8*(r>>2)+4*hi
    const float il = 1.0f / l_run;
    short* orow = o_h + ((size_t)n * T_DIM + qrow) * HD;
#pragma unroll
    for (int rq = 0; rq < 4; ++rq) {
        uint2 st;
        st.x = cvtpk_bf16(accA[rq * 4 + 0] * il, accA[rq * 4 + 1] * il);
        st.y = cvtpk_bf16(accA[rq * 4 + 2] * il, accA[rq * 4 + 3] * il);
        *(uint2*)(orow + rq * 8 + hi * 4) = st;
        uint2 st2;
        st2.x = cvtpk_bf16(accB[rq * 4 + 0] * il, accB[rq * 4 + 1] * il);
        st2.y = cvtpk_bf16(accB[rq * 4 + 2] * il, accB[rq * 4 + 3] * il);
        *(uint2*)(orow + 32 + rq * 8 + hi * 4) = st2;
    }
    if (hi == 0) {
        m_arr[n * T_DIM + qrow] = m_run;
        l_arr[n * T_DIM + qrow] = l_run;
    }
}

// ---------------------------------------------------------------------------
// avg_weights via MFMA (16x16 swapped), exp2 domain to match attn's m,l.
// ---------------------------------------------------------------------------
__global__ __launch_bounds__(256)
void colsum_mfma(const short* __restrict__ q_h, const short* __restrict__ k_h,
                 const float* __restrict__ m_arr, const float* __restrict__ l_arr,
                 float* __restrict__ avg_out)
{
    __shared__ short Qs[64][72];
    __shared__ float ms[64];
    __shared__ float li[64];

    const int n = blockIdx.y, s0 = blockIdx.x * 64;
    const int tid = threadIdx.x, l = tid & 63, w = tid >> 6;
    const int lr = l & 15, lg = l >> 4;

    bf16x8 ak[2];
#pragma unroll
    for (int c = 0; c < 2; ++c)
        ak[c] = *reinterpret_cast<const bf16x8*>(
            k_h + ((size_t)n * SPAD + s0 + w * 16 + lr) * HD + c * 32 + lg * 8);

    float csum[4] = {0.f, 0.f, 0.f, 0.f};

    for (int qo = 0; qo < T_DIM; qo += 64) {
#pragma unroll
        for (int it = 0; it < 2; ++it) {
            const int idx = it * 256 + tid;
            const int row = idx >> 3, cg = idx & 7;
            *reinterpret_cast<bf16x8*>(&Qs[row][cg * 8]) =
                *reinterpret_cast<const bf16x8*>(q_h + ((size_t)n * T_DIM + qo + row) * HD + cg * 8);
        }
        if (tid < 64) ms[tid] = m_arr[n * T_DIM + qo + tid];
        else if (tid < 128) li[tid - 64] = 1.0f / l_arr[n * T_DIM + qo + tid - 64];
        __syncthreads();
#pragma unroll
        for (int qt = 0; qt < 4; ++qt) {
            bf16x8 bq0 = *reinterpret_cast<const bf16x8*>(&Qs[qt * 16 + lr][lg * 8]);
            bf16x8 bq1 = *reinterpret_cast<const bf16x8*>(&Qs[qt * 16 + lr][32 + lg * 8]);
            f32x4 z = {0.f, 0.f, 0.f, 0.f};
            z = __builtin_amdgcn_mfma_f32_16x16x32_bf16(ak[0], bq0, z, 0, 0, 0);
            z = __builtin_amdgcn_mfma_f32_16x16x32_bf16(ak[1], bq1, z, 0, 0, 0);
            const float mq = ms[qt * 16 + lr];
            const float lq = li[qt * 16 + lr];
#pragma unroll
            for (int r = 0; r < 4; ++r)
                csum[r] += exp2_fast(z[r] - mq) * lq;
        }
        __syncthreads();
    }
#pragma unroll
    for (int r = 0; r < 4; ++r) {
        float v = csum[r];
        v += __shfl_xor(v, 1, 16);
        v += __shfl_xor(v, 2, 16);
        v += __shfl_xor(v, 4, 16);
        v += __shfl_xor(v, 8, 16);
        if (lr == 0) {
            const int key = s0 + w * 16 + lg * 4 + r;
            if (key < SP1) avg_out[(size_t)n * SP1 + key] = v * 0.0625f;
        }
    }
}

// ---------------------------------------------------------------------------
extern "C" void kernel_launch(void* const* d_in, const int* in_sizes, int n_in,
                              void* d_out, int out_size, void* d_ws, size_t ws_size,
                              hipStream_t stream)
{
    const float* query   = (const float*)d_in[0];
    const float* key     = (const float*)d_in[1];
    const float* value   = (const float*)d_in[2];
    const float* wq      = (const float*)d_in[3];
    const float* wk      = (const float*)d_in[4];
    const float* wv      = (const float*)d_in[5];
    const float* in_bias = (const float*)d_in[6];
    const float* bias_k  = (const float*)d_in[7];
    const float* bias_v  = (const float*)d_in[8];
    const float* wo      = (const float*)d_in[9];
    const float* out_b   = (const float*)d_in[10];
    float* out = (float*)d_out;

    const size_t NTOK = (size_t)T_DIM * B_DIM;
    short* qx  = (short*)d_ws;
    short* kx  = qx  + NTOK * E_DIM;
    short* vx  = kx  + NTOK * E_DIM;
    short* wqb = vx  + NTOK * E_DIM;
    short* wkb = wqb + (size_t)E_DIM * E_DIM;
    short* wvb = wkb + (size_t)E_DIM * E_DIM;
    short* wob = wvb + (size_t)E_DIM * E_DIM;
    short* q_h = wob + (size_t)E_DIM * E_DIM;
    short* k_h = q_h + (size_t)NH * T_DIM * HD;
    short* v_h = k_h + (size_t)NH * SPAD * HD;
    short* o_h = v_h + (size_t)NH * SPAD * HD;
    float* m_arr = (float*)(o_h + (size_t)NH * T_DIM * HD);
    float* l_arr = m_arr + (size_t)NH * T_DIM;

    const int n8_x = (int)(NTOK * E_DIM / 8);
    const int n8_w = E_DIM * E_DIM / 8;
    const dim3 blk(256);
    hipLaunchKernelGGL(cvt_bf16_k, dim3((n8_x + 255) / 256), blk, 0, stream, query, qx, n8_x);
    hipLaunchKernelGGL(cvt_bf16_k, dim3((n8_x + 255) / 256), blk, 0, stream, key,   kx, n8_x);
    hipLaunchKernelGGL(cvt_bf16_k, dim3((n8_x + 255) / 256), blk, 0, stream, value, vx, n8_x);
    hipLaunchKernelGGL(cvt_bf16_k, dim3((n8_w + 255) / 256), blk, 0, stream, wq, wqb, n8_w);
    hipLaunchKernelGGL(cvt_bf16_k, dim3((n8_w + 255) / 256), blk, 0, stream, wk, wkb, n8_w);
    hipLaunchKernelGGL(cvt_bf16_k, dim3((n8_w + 255) / 256), blk, 0, stream, wv, wvb, n8_w);
    hipLaunchKernelGGL(cvt_bf16_k, dim3((n8_w + 255) / 256), blk, 0, stream, wo, wob, n8_w);

    const dim3 gg(64, 8);
    hipLaunchKernelGGL((gemm_bf16<0>), gg, blk, 0, stream, qx, wqb, in_bias,             (void*)q_h);
    hipLaunchKernelGGL((gemm_bf16<1>), gg, blk, 0, stream, kx, wkb, in_bias + E_DIM,     (void*)k_h);
    hipLaunchKernelGGL((gemm_bf16<2>), gg, blk, 0, stream, vx, wvb, in_bias + 2 * E_DIM, (void*)v_h);
    hipLaunchKernelGGL(fill_kv_pad, dim3(SPAD - S_DIM, NH), dim3(64), 0, stream,
                       k_h, v_h, bias_k, bias_v);
    hipLaunchKernelGGL(attn_mfma, dim3(T_DIM / 128, NH), blk, 0, stream,
                       q_h, k_h, v_h, o_h, m_arr, l_arr);
    hipLaunchKernelGGL(colsum_mfma, dim3(NCHUNK, NH), blk, 0, stream,
                       q_h, k_h, m_arr, l_arr, out + (size_t)T_DIM * B_DIM * E_DIM);
    hipLaunchKernelGGL((gemm_bf16<3>), gg, blk, 0, stream, o_h, wob, out_b, (void*)out);
}

// Round 4
// 303.474 us; speedup vs baseline: 22.3106x; 1.1001x over previous
//
#include <hip/hip_runtime.h>

#define T_DIM 2048
#define B_DIM 4
#define S_DIM 2048
#define E_DIM 1024
#define H_NUM 16
#define HD    64
#define NH    64      // B*H
#define SP1   2049    // S+1 (bias token appended)
#define SPAD  2112    // 33*64, padded key length
#define NCHUNK 33

typedef short bf16x8 __attribute__((ext_vector_type(8)));
typedef float f32x4  __attribute__((ext_vector_type(4)));
typedef float f32x16 __attribute__((ext_vector_type(16)));
typedef unsigned int u32;

// log2(e): softmax done in exp2 domain; folded into Q projection scale.
#define QSCALE 0.18033688011112042f   // 0.125 * log2(e)

#if __has_builtin(__builtin_amdgcn_exp2f)
__device__ __forceinline__ float exp2_fast(float x) { return __builtin_amdgcn_exp2f(x); }
#else
__device__ __forceinline__ float exp2_fast(float x) { return __expf(x * 0.6931471805599453f); }
#endif

__device__ __forceinline__ unsigned short f2bf(float x) {
    union { float f; unsigned int u; } v; v.f = x;
    unsigned int r = v.u + 0x7FFFu + ((v.u >> 16) & 1u);   // RNE
    return (unsigned short)(r >> 16);
}

__device__ __forceinline__ u32 cvtpk_bf16(float lo, float hi) {
    u32 r;
    asm("v_cvt_pk_bf16_f32 %0, %1, %2" : "=v"(r) : "v"(lo), "v"(hi));
    return r;
}
__device__ __forceinline__ void plswap(u32& a, u32& b) {
    asm("v_permlane32_swap_b32 %0, %1" : "+v"(a), "+v"(b));
}

// ---------------------------------------------------------------------------
// f32 -> bf16 bulk convert (weights only now)
// ---------------------------------------------------------------------------
__global__ __launch_bounds__(256)
void cvt_bf16_k(const float* __restrict__ src, short* __restrict__ dst, int n8)
{
    int i = blockIdx.x * 256 + threadIdx.x;
    if (i >= n8) return;
    const float4* s = reinterpret_cast<const float4*>(src) + (size_t)i * 2;
    float4 a = s[0], b = s[1];
    bf16x8 o;
    o[0] = (short)f2bf(a.x); o[1] = (short)f2bf(a.y);
    o[2] = (short)f2bf(a.z); o[3] = (short)f2bf(a.w);
    o[4] = (short)f2bf(b.x); o[5] = (short)f2bf(b.y);
    o[6] = (short)f2bf(b.z); o[7] = (short)f2bf(b.w);
    *(reinterpret_cast<bf16x8*>(dst) + i) = o;
}

// ---------------------------------------------------------------------------
// bf16 MFMA GEMM. MODE 0..2: A is f32 (converted inline during staging).
// MODE 3: A is bf16, gathered from head-major o_h.
// ---------------------------------------------------------------------------
template<int MODE>
__global__ __launch_bounds__(256)
void gemm_bf16(const void* __restrict__ Ap, const short* __restrict__ W,
               const float* __restrict__ bias, void* __restrict__ outp)
{
    __shared__ short As[128][72];
    __shared__ short Bs[128][72];
    const int bm = blockIdx.x, bn = blockIdx.y;
    const int tid = threadIdx.x;
    const int l = tid & 63, w = tid >> 6;
    const int wr = w >> 1, wc = w & 1;
    const int lr = l & 15, lg = l >> 4;

    f32x4 acc[4][4] = {};

    for (int k0 = 0; k0 < E_DIM; k0 += 64) {
#pragma unroll
        for (int it = 0; it < 4; ++it) {
            const int idx = it * 256 + tid;
            const int row = idx >> 3, cg = idx & 7;
            if (MODE == 3) {
                const int m = bm * 128 + row;
                const size_t asrc =
                    ((size_t)((m & 3) * 16 + (k0 >> 6)) * T_DIM + (m >> 2)) * HD + cg * 8;
                *reinterpret_cast<bf16x8*>(&As[row][cg * 8]) =
                    *reinterpret_cast<const bf16x8*>((const short*)Ap + asrc);
            } else {
                const float* ap = (const float*)Ap + (size_t)(bm * 128 + row) * E_DIM + k0 + cg * 8;
                const float4 a0 = *reinterpret_cast<const float4*>(ap);
                const float4 a1 = *reinterpret_cast<const float4*>(ap + 4);
                uint4 st;
                st.x = cvtpk_bf16(a0.x, a0.y); st.y = cvtpk_bf16(a0.z, a0.w);
                st.z = cvtpk_bf16(a1.x, a1.y); st.w = cvtpk_bf16(a1.z, a1.w);
                *reinterpret_cast<uint4*>(&As[row][cg * 8]) = st;
            }
            *reinterpret_cast<bf16x8*>(&Bs[row][cg * 8]) =
                *reinterpret_cast<const bf16x8*>(W + (size_t)(bn * 128 + row) * E_DIM + k0 + cg * 8);
        }
        __syncthreads();
        __builtin_amdgcn_s_setprio(1);
#pragma unroll
        for (int c = 0; c < 2; ++c) {
            bf16x8 af[4], bf[4];
#pragma unroll
            for (int mi = 0; mi < 4; ++mi)
                af[mi] = *reinterpret_cast<const bf16x8*>(&As[wr * 64 + mi * 16 + lr][c * 32 + lg * 8]);
#pragma unroll
            for (int ni = 0; ni < 4; ++ni)
                bf[ni] = *reinterpret_cast<const bf16x8*>(&Bs[wc * 64 + ni * 16 + lr][c * 32 + lg * 8]);
#pragma unroll
            for (int mi = 0; mi < 4; ++mi)
#pragma unroll
                for (int ni = 0; ni < 4; ++ni)
                    acc[mi][ni] = __builtin_amdgcn_mfma_f32_16x16x32_bf16(
                        af[mi], bf[ni], acc[mi][ni], 0, 0, 0);
        }
        __builtin_amdgcn_s_setprio(0);
        __syncthreads();
    }

#pragma unroll
    for (int mi = 0; mi < 4; ++mi)
#pragma unroll
        for (int ni = 0; ni < 4; ++ni) {
            const int colg = bn * 128 + wc * 64 + ni * 16 + lr;
            const float bv = bias[colg];
#pragma unroll
            for (int r = 0; r < 4; ++r) {
                const int m = bm * 128 + wr * 64 + mi * 16 + lg * 4 + r;
                float v = acc[mi][ni][r] + bv;
                if (MODE == 3) {
                    ((float*)outp)[(size_t)m * E_DIM + colg] = v;
                } else {
                    if (MODE == 0) v *= QSCALE;
                    const int seq = m >> 2, b = m & 3;
                    const int head = colg >> 6, d = colg & 63;
                    const int sd = (MODE == 0) ? T_DIM : SPAD;
                    ((short*)outp)[((size_t)(b * 16 + head) * sd + seq) * HD + d] = (short)f2bf(v);
                }
            }
        }
}

// append bias_k/bias_v token at s=2048 (bf16), zero rows 2049..2111
__global__ void fill_kv_pad(short* __restrict__ k_h, short* __restrict__ v_h,
                            const float* __restrict__ bias_k,
                            const float* __restrict__ bias_v)
{
    const int d   = threadIdx.x;
    const int row = S_DIM + blockIdx.x;
    const int n   = blockIdx.y;
    short bk = 0, bv = 0;
    if (row == S_DIM) {
        bk = (short)f2bf(bias_k[(n & 15) * HD + d]);
        bv = (short)f2bf(bias_v[(n & 15) * HD + d]);
    }
    const size_t idx = ((size_t)n * SPAD + row) * HD + d;
    k_h[idx] = bk;
    v_h[idx] = bv;
}

// ---------------------------------------------------------------------------
// Swapped 32x32 MFMA flash attention, now with register-prefetch staging
// (T14) + LDS double-buffer -> 1 barrier per chunk, HBM latency hidden.
// ---------------------------------------------------------------------------
__global__ __launch_bounds__(256)
void attn_mfma(const short* __restrict__ q_h, const short* __restrict__ k_h,
               const short* __restrict__ v_h, short* __restrict__ o_h,
               float* __restrict__ m_arr, float* __restrict__ l_arr)
{
    __shared__ short KsD[2][64 * 64];
    __shared__ short VtD[2][64 * 64];

    const int n = blockIdx.y, q0 = blockIdx.x * 128;
    const int tid = threadIdx.x, l = tid & 63, w = tid >> 6;
    const int ql = l & 31;
    const int hi = l >> 5;
    const int qrow = q0 + w * 32 + ql;

    // staging coords
    const int krow = tid >> 3, kcg = tid & 7;
    const int kswz = (kcg * 16) ^ ((krow & 7) << 4);
    const int sp = tid & 31, d0 = (tid >> 5) * 8;

    const short* kbase = k_h + (size_t)n * SPAD * HD;
    const short* vbase = v_h + (size_t)n * SPAD * HD;

    // Q fragments: B[col=q][k]; lane q = ql, k = sl*16 + hi*8 + j
    bf16x8 aq0, aq1, aq2, aq3;
    {
        const short* qp = q_h + ((size_t)n * T_DIM + qrow) * HD + hi * 8;
        aq0 = *(const bf16x8*)(qp);
        aq1 = *(const bf16x8*)(qp + 16);
        aq2 = *(const bf16x8*)(qp + 32);
        aq3 = *(const bf16x8*)(qp + 48);
    }

    // prologue: chunk 0 -> regs -> LDS buf 0
    bf16x8 pk0 = *(const bf16x8*)(kbase + (size_t)krow * HD + kcg * 8);
    bf16x8 pk1 = *(const bf16x8*)(kbase + (size_t)(32 + krow) * HD + kcg * 8);
    bf16x8 pv0 = *(const bf16x8*)(vbase + (size_t)(2 * sp) * HD + d0);
    bf16x8 pv1 = *(const bf16x8*)(vbase + (size_t)(2 * sp + 1) * HD + d0);
    {
        char* KsB = (char*)KsD[0];
        char* VtB = (char*)VtD[0];
        *(bf16x8*)(KsB + krow * 128 + kswz) = pk0;
        *(bf16x8*)(KsB + (32 + krow) * 128 + kswz) = pk1;
#pragma unroll
        for (int j = 0; j < 8; ++j) {
            u32 pk = (u32)(unsigned short)pv0[j] | ((u32)(unsigned short)pv1[j] << 16);
            const int d = d0 + j;
            *(u32*)(VtB + d * 128 + ((4 * sp) ^ ((d & 7) << 4))) = pk;
        }
    }
    __syncthreads();

    float m_run = -1e30f, l_run = 0.f;
    f32x16 accA, accB;
#pragma unroll
    for (int r = 0; r < 16; ++r) { accA[r] = 0.f; accB[r] = 0.f; }

    for (int kc = 0; kc < NCHUNK; ++kc) {
        const char* KsB = (const char*)KsD[kc & 1];
        const char* VtB = (const char*)VtD[kc & 1];
        const bool more = (kc + 1 < NCHUNK);

        // ---- issue prefetch for chunk kc+1 (latency hidden under compute) --
        if (more) {
            const int s0n = (kc + 1) * 64;
            pk0 = *(const bf16x8*)(kbase + (size_t)(s0n + krow) * HD + kcg * 8);
            pk1 = *(const bf16x8*)(kbase + (size_t)(s0n + 32 + krow) * HD + kcg * 8);
            pv0 = *(const bf16x8*)(vbase + (size_t)(s0n + 2 * sp) * HD + d0);
            pv1 = *(const bf16x8*)(vbase + (size_t)(s0n + 2 * sp + 1) * HD + d0);
        }

        // ---- QK^T: S^T tiles, lane col = q ----
        f32x16 sc0, sc1;
#pragma unroll
        for (int r = 0; r < 16; ++r) { sc0[r] = 0.f; sc1[r] = 0.f; }
        __builtin_amdgcn_s_setprio(1);
#pragma unroll
        for (int sl = 0; sl < 4; ++sl) {
            const int cb = ((sl * 32) + hi * 16) ^ ((ql & 7) << 4);
            bf16x8 kf0 = *(const bf16x8*)(KsB + ql * 128 + cb);
            bf16x8 kf1 = *(const bf16x8*)(KsB + (32 + ql) * 128 + cb);
            bf16x8 qf = (sl == 0) ? aq0 : (sl == 1) ? aq1 : (sl == 2) ? aq2 : aq3;
            sc0 = __builtin_amdgcn_mfma_f32_32x32x16_bf16(kf0, qf, sc0, 0, 0, 0);
            sc1 = __builtin_amdgcn_mfma_f32_32x32x16_bf16(kf1, qf, sc1, 0, 0, 0);
        }
        __builtin_amdgcn_s_setprio(0);

        // ---- mask invalid keys (last chunk only) ----
        const int s0 = kc * 64;
        if (s0 + 64 > SP1) {
#pragma unroll
            for (int r = 0; r < 16; ++r) {
                const int key = (r & 3) + 8 * (r >> 2) + 4 * hi;
                if (s0 + key >= SP1)      sc0[r] = -1e30f;
                if (s0 + 32 + key >= SP1) sc1[r] = -1e30f;
            }
        }

        // ---- online softmax (exp2 domain), defer-max THR=8 ----
        float mx = sc0[0];
#pragma unroll
        for (int r = 1; r < 16; ++r) mx = fmaxf(mx, sc0[r]);
#pragma unroll
        for (int r = 0; r < 16; ++r) mx = fmaxf(mx, sc1[r]);
        mx = fmaxf(mx, __shfl_xor(mx, 32));
        if (!__all(mx - m_run <= 8.0f)) {
            const float mnew = fmaxf(m_run, mx);
            const float fac = exp2_fast(m_run - mnew);
            l_run *= fac;
#pragma unroll
            for (int r = 0; r < 16; ++r) { accA[r] *= fac; accB[r] *= fac; }
            m_run = mnew;
        }
        float ps = 0.f;
        float p0[16], p1[16];
#pragma unroll
        for (int r = 0; r < 16; ++r) { p0[r] = exp2_fast(sc0[r] - m_run); ps += p0[r]; }
#pragma unroll
        for (int r = 0; r < 16; ++r) { p1[r] = exp2_fast(sc1[r] - m_run); ps += p1[r]; }
        ps += __shfl_xor(ps, 32);
        l_run += ps;

        // ---- P fragments in-register (cvt_pk + permlane32_swap) ----
        union PF { u32 u[4]; bf16x8 v; };
        PF pf0, pf1, pf2, pf3;
        {
            u32 a0 = cvtpk_bf16(p0[0], p0[1]),   b0 = cvtpk_bf16(p0[4], p0[5]);   plswap(a0, b0);
            u32 a1 = cvtpk_bf16(p0[2], p0[3]),   b1 = cvtpk_bf16(p0[6], p0[7]);   plswap(a1, b1);
            u32 a2 = cvtpk_bf16(p0[8], p0[9]),   b2 = cvtpk_bf16(p0[12], p0[13]); plswap(a2, b2);
            u32 a3 = cvtpk_bf16(p0[10], p0[11]), b3 = cvtpk_bf16(p0[14], p0[15]); plswap(a3, b3);
            pf0.u[0] = a0; pf0.u[1] = a1; pf0.u[2] = b0; pf0.u[3] = b1;
            pf1.u[0] = a2; pf1.u[1] = a3; pf1.u[2] = b2; pf1.u[3] = b3;
            u32 c0 = cvtpk_bf16(p1[0], p1[1]),   d0_ = cvtpk_bf16(p1[4], p1[5]);   plswap(c0, d0_);
            u32 c1 = cvtpk_bf16(p1[2], p1[3]),   d1_ = cvtpk_bf16(p1[6], p1[7]);   plswap(c1, d1_);
            u32 c2 = cvtpk_bf16(p1[8], p1[9]),   d2_ = cvtpk_bf16(p1[12], p1[13]); plswap(c2, d2_);
            u32 c3 = cvtpk_bf16(p1[10], p1[11]), d3_ = cvtpk_bf16(p1[14], p1[15]); plswap(c3, d3_);
            pf2.u[0] = c0; pf2.u[1] = c1; pf2.u[2] = d0_; pf2.u[3] = d1_;
            pf3.u[0] = c2; pf3.u[1] = c3; pf3.u[2] = d2_; pf3.u[3] = d3_;
        }

        // ---- PV: O^T += Vt @ P ----
        __builtin_amdgcn_s_setprio(1);
#pragma unroll
        for (int ksl = 0; ksl < 4; ++ksl) {
            const int cb = ((ksl * 32) + hi * 16) ^ ((ql & 7) << 4);
            bf16x8 vf0 = *(const bf16x8*)(VtB + ql * 128 + cb);
            bf16x8 vf1 = *(const bf16x8*)(VtB + (32 + ql) * 128 + cb);
            const bf16x8 pv = (ksl == 0) ? pf0.v : (ksl == 1) ? pf1.v : (ksl == 2) ? pf2.v : pf3.v;
            accA = __builtin_amdgcn_mfma_f32_32x32x16_bf16(vf0, pv, accA, 0, 0, 0);
            accB = __builtin_amdgcn_mfma_f32_32x32x16_bf16(vf1, pv, accB, 0, 0, 0);
        }
        __builtin_amdgcn_s_setprio(0);

        // ---- write prefetched chunk to other buffer, single barrier ----
        if (more) {
            char* KsN = (char*)KsD[(kc & 1) ^ 1];
            char* VtN = (char*)VtD[(kc & 1) ^ 1];
            *(bf16x8*)(KsN + krow * 128 + kswz) = pk0;
            *(bf16x8*)(KsN + (32 + krow) * 128 + kswz) = pk1;
#pragma unroll
            for (int j = 0; j < 8; ++j) {
                u32 pk = (u32)(unsigned short)pv0[j] | ((u32)(unsigned short)pv1[j] << 16);
                const int d = d0 + j;
                *(u32*)(VtN + d * 128 + ((4 * sp) ^ ((d & 7) << 4))) = pk;
            }
            __syncthreads();
        }
    }

    // ---- epilogue ----
    const float il = 1.0f / l_run;
    short* orow = o_h + ((size_t)n * T_DIM + qrow) * HD;
#pragma unroll
    for (int rq = 0; rq < 4; ++rq) {
        uint2 st;
        st.x = cvtpk_bf16(accA[rq * 4 + 0] * il, accA[rq * 4 + 1] * il);
        st.y = cvtpk_bf16(accA[rq * 4 + 2] * il, accA[rq * 4 + 3] * il);
        *(uint2*)(orow + rq * 8 + hi * 4) = st;
        uint2 st2;
        st2.x = cvtpk_bf16(accB[rq * 4 + 0] * il, accB[rq * 4 + 1] * il);
        st2.y = cvtpk_bf16(accB[rq * 4 + 2] * il, accB[rq * 4 + 3] * il);
        *(uint2*)(orow + 32 + rq * 8 + hi * 4) = st2;
    }
    if (hi == 0) {
        m_arr[n * T_DIM + qrow] = m_run;
        l_arr[n * T_DIM + qrow] = l_run;
    }
}

// ---------------------------------------------------------------------------
// avg_weights: reg-prefetch + double-buffered Q staging, 1 barrier/iter.
// ---------------------------------------------------------------------------
__global__ __launch_bounds__(256)
void colsum_mfma(const short* __restrict__ q_h, const short* __restrict__ k_h,
                 const float* __restrict__ m_arr, const float* __restrict__ l_arr,
                 float* __restrict__ avg_out)
{
    __shared__ short Qs[2][64][72];
    __shared__ float msh[2][64];
    __shared__ float lih[2][64];

    const int n = blockIdx.y, s0 = blockIdx.x * 64;
    const int tid = threadIdx.x, l = tid & 63, w = tid >> 6;
    const int lr = l & 15, lg = l >> 4;
    const int qr = tid >> 3, qcg = tid & 7;

    const short* qbase = q_h + (size_t)n * T_DIM * HD;

    bf16x8 ak[2];
#pragma unroll
    for (int c = 0; c < 2; ++c)
        ak[c] = *reinterpret_cast<const bf16x8*>(
            k_h + ((size_t)n * SPAD + s0 + w * 16 + lr) * HD + c * 32 + lg * 8);

    // prologue: Q tile 0 -> regs -> buf 0
    bf16x8 qa = *(const bf16x8*)(qbase + (size_t)qr * HD + qcg * 8);
    bf16x8 qb = *(const bf16x8*)(qbase + (size_t)(32 + qr) * HD + qcg * 8);
    float mlv = 0.f;
    if (tid < 64) mlv = m_arr[n * T_DIM + tid];
    else if (tid < 128) mlv = l_arr[n * T_DIM + tid - 64];
    *(bf16x8*)&Qs[0][qr][qcg * 8] = qa;
    *(bf16x8*)&Qs[0][32 + qr][qcg * 8] = qb;
    if (tid < 64) msh[0][tid] = mlv;
    else if (tid < 128) lih[0][tid - 64] = 1.0f / mlv;
    __syncthreads();

    float csum[4] = {0.f, 0.f, 0.f, 0.f};

    for (int it = 0; it < T_DIM / 64; ++it) {
        const int buf = it & 1;
        const bool more = (it + 1 < T_DIM / 64);
        if (more) {
            const int qo = (it + 1) * 64;
            qa = *(const bf16x8*)(qbase + (size_t)(qo + qr) * HD + qcg * 8);
            qb = *(const bf16x8*)(qbase + (size_t)(qo + 32 + qr) * HD + qcg * 8);
            if (tid < 64) mlv = m_arr[n * T_DIM + qo + tid];
            else if (tid < 128) mlv = l_arr[n * T_DIM + qo + tid - 64];
        }
        __builtin_amdgcn_s_setprio(1);
#pragma unroll
        for (int qt = 0; qt < 4; ++qt) {
            bf16x8 bq0 = *reinterpret_cast<const bf16x8*>(&Qs[buf][qt * 16 + lr][lg * 8]);
            bf16x8 bq1 = *reinterpret_cast<const bf16x8*>(&Qs[buf][qt * 16 + lr][32 + lg * 8]);
            f32x4 z = {0.f, 0.f, 0.f, 0.f};
            z = __builtin_amdgcn_mfma_f32_16x16x32_bf16(ak[0], bq0, z, 0, 0, 0);
            z = __builtin_amdgcn_mfma_f32_16x16x32_bf16(ak[1], bq1, z, 0, 0, 0);
            const float mq = msh[buf][qt * 16 + lr];
            const float lq = lih[buf][qt * 16 + lr];
#pragma unroll
            for (int r = 0; r < 4; ++r)
                csum[r] += exp2_fast(z[r] - mq) * lq;
        }
        __builtin_amdgcn_s_setprio(0);
        if (more) {
            *(bf16x8*)&Qs[buf ^ 1][qr][qcg * 8] = qa;
            *(bf16x8*)&Qs[buf ^ 1][32 + qr][qcg * 8] = qb;
            if (tid < 64) msh[buf ^ 1][tid] = mlv;
            else if (tid < 128) lih[buf ^ 1][tid - 64] = 1.0f / mlv;
            __syncthreads();
        }
    }

#pragma unroll
    for (int r = 0; r < 4; ++r) {
        float v = csum[r];
        v += __shfl_xor(v, 1, 16);
        v += __shfl_xor(v, 2, 16);
        v += __shfl_xor(v, 4, 16);
        v += __shfl_xor(v, 8, 16);
        if (lr == 0) {
            const int key = s0 + w * 16 + lg * 4 + r;
            if (key < SP1) avg_out[(size_t)n * SP1 + key] = v * 0.0625f;
        }
    }
}

// ---------------------------------------------------------------------------
extern "C" void kernel_launch(void* const* d_in, const int* in_sizes, int n_in,
                              void* d_out, int out_size, void* d_ws, size_t ws_size,
                              hipStream_t stream)
{
    const float* query   = (const float*)d_in[0];
    const float* key     = (const float*)d_in[1];
    const float* value   = (const float*)d_in[2];
    const float* wq      = (const float*)d_in[3];
    const float* wk      = (const float*)d_in[4];
    const float* wv      = (const float*)d_in[5];
    const float* in_bias = (const float*)d_in[6];
    const float* bias_k  = (const float*)d_in[7];
    const float* bias_v  = (const float*)d_in[8];
    const float* wo      = (const float*)d_in[9];
    const float* out_b   = (const float*)d_in[10];
    float* out = (float*)d_out;

    short* wqb = (short*)d_ws;                           // [1024][1024] bf16 x4
    short* wkb = wqb + (size_t)E_DIM * E_DIM;
    short* wvb = wkb + (size_t)E_DIM * E_DIM;
    short* wob = wvb + (size_t)E_DIM * E_DIM;
    short* q_h = wob + (size_t)E_DIM * E_DIM;            // [64][2048][64]
    short* k_h = q_h + (size_t)NH * T_DIM * HD;          // [64][2112][64]
    short* v_h = k_h + (size_t)NH * SPAD * HD;           // [64][2112][64]
    short* o_h = v_h + (size_t)NH * SPAD * HD;           // [64][2048][64]
    float* m_arr = (float*)(o_h + (size_t)NH * T_DIM * HD);
    float* l_arr = m_arr + (size_t)NH * T_DIM;

    const int n8_w = E_DIM * E_DIM / 8;
    const dim3 blk(256);
    hipLaunchKernelGGL(cvt_bf16_k, dim3((n8_w + 255) / 256), blk, 0, stream, wq, wqb, n8_w);
    hipLaunchKernelGGL(cvt_bf16_k, dim3((n8_w + 255) / 256), blk, 0, stream, wk, wkb, n8_w);
    hipLaunchKernelGGL(cvt_bf16_k, dim3((n8_w + 255) / 256), blk, 0, stream, wv, wvb, n8_w);
    hipLaunchKernelGGL(cvt_bf16_k, dim3((n8_w + 255) / 256), blk, 0, stream, wo, wob, n8_w);

    const dim3 gg(64, 8);
    hipLaunchKernelGGL((gemm_bf16<0>), gg, blk, 0, stream, (const void*)query, wqb, in_bias,             (void*)q_h);
    hipLaunchKernelGGL((gemm_bf16<1>), gg, blk, 0, stream, (const void*)key,   wkb, in_bias + E_DIM,     (void*)k_h);
    hipLaunchKernelGGL((gemm_bf16<2>), gg, blk, 0, stream, (const void*)value, wvb, in_bias + 2 * E_DIM, (void*)v_h);
    hipLaunchKernelGGL(fill_kv_pad, dim3(SPAD - S_DIM, NH), dim3(64), 0, stream,
                       k_h, v_h, bias_k, bias_v);
    hipLaunchKernelGGL(attn_mfma, dim3(T_DIM / 128, NH), blk, 0, stream,
                       q_h, k_h, v_h, o_h, m_arr, l_arr);
    hipLaunchKernelGGL(colsum_mfma, dim3(NCHUNK, NH), blk, 0, stream,
                       q_h, k_h, m_arr, l_arr, out + (size_t)T_DIM * B_DIM * E_DIM);
    hipLaunchKernelGGL((gemm_bf16<3>), gg, blk, 0, stream, (const void*)o_h, wob, out_b, (void*)out);
}